// Round 6
// baseline (233.325 us; speedup 1.0000x reference)
//
#include <hip/hip_runtime.h>

// DynamicConv2d: B=16, CIN=COUT=64, K=3, H=W=192, OH=OW=190, DEG=64, HID=256
// out[b][co][oy][ox] = sum_{ci,ky,kx} w[b][co][ci][ky][kx] * x[b][ci][oy+ky][ox+kx]
// w = (relu(deg@W1+b1)@W2+b2).reshape(B,COUT,CIN,3,3)

typedef __bf16 bf16x8 __attribute__((ext_vector_type(8)));
typedef float  f32x4  __attribute__((ext_vector_type(4)));

#define NB   16
#define CIN  64
#define COUT 64
#define HW   192
#define OHW  190
#define NPIX (HW*HW)        // 36864
#define NW2  (COUT*CIN*9)   // 36864

__device__ __forceinline__ unsigned short f2bf(float f) {
    union { float f; unsigned int u; } v; v.f = f;
    unsigned int r = v.u + 0x7FFFu + ((v.u >> 16) & 1u);   // RNE
    return (unsigned short)(r >> 16);
}

// async global->LDS, 16B per lane. LDS dest: wave-uniform base + lane*16.
__device__ __forceinline__ void async_copy16(const void* gsrc, void* ldst) {
    __builtin_amdgcn_global_load_lds(
        (const __attribute__((address_space(1))) unsigned int*)gsrc,
        (__attribute__((address_space(3))) unsigned int*)ldst, 16, 0, 0);
}

// ---------------- k1: h = relu(deg @ W1 + b1)  [16,256] ----------------
__global__ void k1_hidden(const float* __restrict__ deg, const float* __restrict__ W1,
                          const float* __restrict__ b1, float* __restrict__ h) {
    int b = blockIdx.x, j = threadIdx.x;
    float acc = b1[j];
    for (int d = 0; d < 64; ++d) acc += deg[b*64 + d] * W1[d*256 + j];
    h[b*256 + j] = fmaxf(acc, 0.f);
}

// ---------------- k2: weights = h @ W2 + b2 -> Aw[b][tap][co][ci] bf16 ----------------
__global__ void k2_wgen(const float* __restrict__ h, const float* __restrict__ W2,
                        const float* __restrict__ b2, unsigned short* __restrict__ Aw) {
    __shared__ float hs[16*256];
    __shared__ float red[8][16][33];
    int t = threadIdx.x;
    for (int i = t; i < 16*256; i += 256) hs[i] = h[i];
    __syncthreads();

    int nl = t & 31;                 // 0..31
    int kc = t >> 5;                 // 0..7
    int n  = blockIdx.x * 32 + nl;
    float acc[16] = {};
    #pragma unroll
    for (int kk = 0; kk < 32; ++kk) {
        int k = kc*32 + kk;
        float w = W2[(size_t)k*NW2 + n];
        #pragma unroll
        for (int b = 0; b < 16; ++b) acc[b] += hs[b*256 + k] * w;
    }
    #pragma unroll
    for (int b = 0; b < 16; ++b) red[kc][b][nl] = acc[b];
    __syncthreads();

    for (int i = t; i < 512; i += 256) {
        int b  = i >> 5;
        int nn = i & 31;
        int n2 = blockIdx.x * 32 + nn;
        float s = b2[n2];
        #pragma unroll
        for (int k = 0; k < 8; ++k) s += red[k][b][nn];
        int co  = n2 / 576;
        int rem = n2 - co*576;
        int ci  = rem / 9;
        int tap = rem - ci*9;
        Aw[(((b*9 + tap)*COUT + co)*CIN) + ci] = f2bf(s);
    }
}

// ---------------- k3: xT[b][p][ci] bf16 = x[b][ci][p] ----------------
__global__ void k3_transpose(const float* __restrict__ x, unsigned short* __restrict__ xT) {
    __shared__ float tile[64][65];
    int b  = blockIdx.y;
    int p0 = blockIdx.x * 64;
    int t  = threadIdx.x;
    const float* xb = x + (size_t)b * CIN * NPIX;
    {
        int c  = (t & 15) * 4;
        int r0 = t >> 4;
        #pragma unroll
        for (int i = 0; i < 4; ++i) {
            int ci = r0 + 16*i;
            float4 v = *(const float4*)(xb + (size_t)ci*NPIX + p0 + c);
            tile[ci][c] = v.x; tile[ci][c+1] = v.y; tile[ci][c+2] = v.z; tile[ci][c+3] = v.w;
        }
    }
    __syncthreads();
    {
        int ci4 = (t & 15) * 4;
        int pr  = t >> 4;
        #pragma unroll
        for (int i = 0; i < 4; ++i) {
            int pl = pr + 16*i;
            uint2 w;
            w.x = (unsigned int)f2bf(tile[ci4  ][pl]) | ((unsigned int)f2bf(tile[ci4+1][pl]) << 16);
            w.y = (unsigned int)f2bf(tile[ci4+2][pl]) | ((unsigned int)f2bf(tile[ci4+3][pl]) << 16);
            *(uint2*)(&xT[((size_t)b*NPIX + p0 + pl)*CIN + ci4]) = w;
        }
    }
}

// ---------------- k4: strip MFMA conv, double-buffered with DISTINCT LDS objects ----------------
// grid 768 (16b x 8 strips(24 rows) x 6 tx) = exactly 3 blocks/CU. Block 256 = 4 waves
// (2 co-half x 2 row-pair). Subtile = 4 rows x 32 cols; strip = 6 subtiles.
// xs0/xs1 are SEPARATE __shared__ objects so ds_reads of one never alias-stall on the
// in-flight global_load_lds DMA into the other. K-loop = 6 steps (cc x kx): batch 8
// B-frag ds_read_b128 (4 rows x 2 colgroups), then 24 MFMAs (ky-reuse: rows r+ky).
// A streams from L2 per step, 1-step-ahead prefetch (a0/a1 double buffer).
__global__ __launch_bounds__(256, 3)
void k4_conv(const unsigned short* __restrict__ xT, const unsigned short* __restrict__ Aw,
             float* __restrict__ out) {
    __shared__ unsigned short xs0[6*34*64];   // 26112 B
    __shared__ unsigned short xs1[6*34*64];   // 26112 B
    const int tid = threadIdx.x;

    // bijective XCD swizzle: 768 % 8 == 0, 96 consecutive wg per XCD
    int bid = blockIdx.x;
    int wg  = (bid & 7) * 96 + (bid >> 3);
    int b     = wg / 48;
    int rem   = wg - b*48;
    int strip = rem / 6;
    int tx    = rem - strip*6;
    const int x0 = tx * 32;
    const int y0 = strip * 24;

    const int wv  = tid >> 6;      // 0..3
    const int mh  = wv >> 1;       // co half
    const int rr  = wv & 1;        // row pair within subtile
    const int l   = tid & 63;
    const int l15 = l & 15;
    const int lg  = l >> 4;        // 0..3

    const unsigned short* xTb = xT + (size_t)b * NPIX * CIN;
    const unsigned short* Al  = Aw + b * (9*COUT*CIN) + (mh*32 + l15)*CIN + lg*8;

    // stage subtile ss (6 rows x 34 px x 64 ci) into dst; pre-swizzled source
    auto STG = [&](unsigned short* dst, int ss) {
        int ybase = y0 + 4*ss;
        #pragma unroll
        for (int it = 0; it < 7; ++it) {
            int sl = it*256 + tid;
            if (sl < 1632) {
                int swc = sl & 7;
                int t2  = sl >> 3;
                int gyl = t2 / 34;
                int gxl = t2 - gyl*34;
                int gy = ybase + gyl; if (gy > 191) gy = 191;
                int gx = x0 + gxl;    if (gx > 191) gx = 191;
                const void* src = xTb + ((size_t)(gy*HW + gx))*CIN + ((swc ^ (gx & 7)) * 8);
                async_copy16(src, dst + (size_t)(it*256 + wv*64)*8);
            }
        }
    };

    // load one A step-column (3 ky-taps x 2 m-frags) for (cc, kx)
    auto LDA = [&](bf16x8 (&dA)[3][2], int cc, int kx) {
        #pragma unroll
        for (int ky = 0; ky < 3; ++ky)
            #pragma unroll
            for (int m = 0; m < 2; ++m)
                dA[ky][m] = *(const bf16x8*)(Al + (ky*3 + kx)*4096 + m*1024 + cc*32);
    };

    bf16x8 a0[3][2], a1[3][2];
    LDA(a0, 0, 0);            // A for step 0
    STG(xs0, 0);
    __syncthreads();          // xs0 + a0 ready

#define SUBTILE(SS, XC, XN, NOTLAST)                                                 \
    {                                                                                \
        if (NOTLAST) STG(XN, (SS)+1);                                                \
        f32x4 acc[2][4] = {};                                                        \
        _Pragma("unroll")                                                            \
        for (int st = 0; st < 6; ++st) {                                             \
            const int cc = st / 3, kx = st - 3*(st/3);                               \
            const int nst = (st + 1) % 6;                                            \
            if (st & 1) LDA(a0, nst/3, nst - 3*(nst/3));                             \
            else        LDA(a1, nst/3, nst - 3*(nst/3));                             \
            bf16x8 bb[4][2];                                                         \
            _Pragma("unroll")                                                        \
            for (int rq = 0; rq < 4; ++rq)                                           \
                _Pragma("unroll")                                                    \
                for (int xb2 = 0; xb2 < 2; ++xb2) {                                  \
                    int gyl = rr*2 + rq;                                             \
                    int gxl = xb2*16 + l15 + kx;                                     \
                    int pch = (cc*4 + lg) ^ (gxl & 7);                               \
                    bb[rq][xb2] = *(const bf16x8*)(&(XC)[((gyl*34 + gxl)*8 + pch)*8]); \
                }                                                                    \
            _Pragma("unroll")                                                        \
            for (int ky = 0; ky < 3; ++ky)                                           \
                _Pragma("unroll")                                                    \
                for (int m = 0; m < 2; ++m)                                          \
                    _Pragma("unroll")                                                \
                    for (int r = 0; r < 2; ++r)                                      \
                        _Pragma("unroll")                                            \
                        for (int xb2 = 0; xb2 < 2; ++xb2)                            \
                            acc[m][r*2+xb2] = __builtin_amdgcn_mfma_f32_16x16x32_bf16( \
                                (st & 1) ? a1[ky][m] : a0[ky][m],                    \
                                bb[r+ky][xb2], acc[m][r*2+xb2], 0, 0, 0);            \
        }                                                                            \
        _Pragma("unroll")                                                            \
        for (int m = 0; m < 2; ++m)                                                  \
            _Pragma("unroll")                                                        \
            for (int r = 0; r < 2; ++r)                                              \
                _Pragma("unroll")                                                    \
                for (int xb2 = 0; xb2 < 2; ++xb2) {                                  \
                    int oy = y0 + 4*(SS) + rr*2 + r;                                 \
                    int ox = x0 + xb2*16 + l15;                                      \
                    if (oy < OHW && ox < OHW) {                                      \
                        f32x4 v = acc[m][r*2+xb2];                                   \
                        _Pragma("unroll")                                            \
                        for (int j = 0; j < 4; ++j) {                                \
                            int co = mh*32 + m*16 + lg*4 + j;                        \
                            out[((size_t)(b*COUT + co)*OHW + oy)*OHW + ox] = v[j];   \
                        }                                                            \
                    }                                                                \
                }                                                                    \
        __syncthreads();                                                             \
    }

    SUBTILE(0, xs0, xs1, 1)
    SUBTILE(1, xs1, xs0, 1)
    SUBTILE(2, xs0, xs1, 1)
    SUBTILE(3, xs1, xs0, 1)
    SUBTILE(4, xs0, xs1, 1)
    SUBTILE(5, xs1, xs0, 0)
#undef SUBTILE
}

extern "C" void kernel_launch(void* const* d_in, const int* in_sizes, int n_in,
                              void* d_out, int out_size, void* d_ws, size_t ws_size,
                              hipStream_t stream) {
    const float* x   = (const float*)d_in[0];
    const float* deg = (const float*)d_in[1];
    const float* W1  = (const float*)d_in[2];
    const float* b1  = (const float*)d_in[3];
    const float* W2  = (const float*)d_in[4];
    const float* b2  = (const float*)d_in[5];
    float* out = (float*)d_out;

    const size_t off_h  = 0;                       // 16 KB
    const size_t off_Aw = 16 * 1024;
    const size_t off_xT = off_Aw + (size_t)NB*9*COUT*CIN*2;   // 16B aligned
    float* h           = (float*)((char*)d_ws + off_h);
    unsigned short* Aw = (unsigned short*)((char*)d_ws + off_Aw);
    unsigned short* xT = (unsigned short*)((char*)d_ws + off_xT);

    k1_hidden<<<16, 256, 0, stream>>>(deg, W1, b1, h);
    k2_wgen<<<NW2/32, 256, 0, stream>>>(h, W2, b2, Aw);
    k3_transpose<<<dim3(NPIX/64, NB), 256, 0, stream>>>(x, xT);
    k4_conv<<<768, 256, 0, stream>>>(xT, Aw, out);
}

// Round 7
// 213.410 us; speedup vs baseline: 1.0933x; 1.0933x over previous
//
#include <hip/hip_runtime.h>

// DynamicConv2d: B=16, CIN=COUT=64, K=3, H=W=192, OH=OW=190, DEG=64, HID=256
// out[b][co][oy][ox] = sum_{ci,ky,kx} w[b][co][ci][ky][kx] * x[b][ci][oy+ky][ox+kx]
// w = (relu(deg@W1+b1)@W2+b2).reshape(B,COUT,CIN,3,3)

typedef __bf16 bf16x8 __attribute__((ext_vector_type(8)));
typedef float  f32x4  __attribute__((ext_vector_type(4)));

#define NB   16
#define CIN  64
#define COUT 64
#define HW   192
#define OHW  190
#define NPIX (HW*HW)        // 36864
#define NW2  (COUT*CIN*9)   // 36864

__device__ __forceinline__ unsigned short f2bf(float f) {
    union { float f; unsigned int u; } v; v.f = f;
    unsigned int r = v.u + 0x7FFFu + ((v.u >> 16) & 1u);   // RNE
    return (unsigned short)(r >> 16);
}

// async global->LDS, 16B per lane. LDS dest: wave-uniform base + lane*16.
__device__ __forceinline__ void async_copy16(const void* gsrc, void* ldst) {
    __builtin_amdgcn_global_load_lds(
        (const __attribute__((address_space(1))) unsigned int*)gsrc,
        (__attribute__((address_space(3))) unsigned int*)ldst, 16, 0, 0);
}

// ---------------- k2: fused weight generator ----------------
// h = relu(deg@W1+b1) recomputed per block (cheap: 1024 FMA/thread prologue),
// then weights = h@W2 + b2 -> Aw[b][tap][co][ci] bf16.
// grid 1152, block 256: 32 n-values x 8 k-chunks + LDS reduce.
__global__ void k2_wgen(const float* __restrict__ deg, const float* __restrict__ W1,
                        const float* __restrict__ b1, const float* __restrict__ W2,
                        const float* __restrict__ b2, unsigned short* __restrict__ Aw) {
    __shared__ float degs[16*64];
    __shared__ float hs[16*256];
    __shared__ float red[8][16][33];
    int t = threadIdx.x;
    for (int i = t; i < 16*64; i += 256) degs[i] = deg[i];
    __syncthreads();
    {   // h[b][t] for all 16 b
        float acc[16];
        float bias = b1[t];
        #pragma unroll
        for (int bb2 = 0; bb2 < 16; ++bb2) acc[bb2] = bias;
        for (int d = 0; d < 64; ++d) {
            float w = W1[d*256 + t];
            #pragma unroll
            for (int bb2 = 0; bb2 < 16; ++bb2) acc[bb2] += degs[bb2*64 + d] * w;
        }
        #pragma unroll
        for (int bb2 = 0; bb2 < 16; ++bb2) hs[bb2*256 + t] = fmaxf(acc[bb2], 0.f);
    }
    __syncthreads();

    int nl = t & 31;                 // 0..31
    int kc = t >> 5;                 // 0..7
    int n  = blockIdx.x * 32 + nl;
    float acc[16] = {};
    #pragma unroll
    for (int kk = 0; kk < 32; ++kk) {
        int k = kc*32 + kk;
        float w = W2[(size_t)k*NW2 + n];
        #pragma unroll
        for (int b = 0; b < 16; ++b) acc[b] += hs[b*256 + k] * w;
    }
    #pragma unroll
    for (int b = 0; b < 16; ++b) red[kc][b][nl] = acc[b];
    __syncthreads();

    for (int i = t; i < 512; i += 256) {
        int b  = i >> 5;
        int nn = i & 31;
        int n2 = blockIdx.x * 32 + nn;
        float s = b2[n2];
        #pragma unroll
        for (int k = 0; k < 8; ++k) s += red[k][b][nn];
        int co  = n2 / 576;
        int rem = n2 - co*576;
        int ci  = rem / 9;
        int tap = rem - ci*9;
        Aw[(((b*9 + tap)*COUT + co)*CIN) + ci] = f2bf(s);
    }
}

// ---------------- k3: xT[b][p][ci] bf16 = x[b][ci][p] ----------------
__global__ void k3_transpose(const float* __restrict__ x, unsigned short* __restrict__ xT) {
    __shared__ float tile[64][65];
    int b  = blockIdx.y;
    int p0 = blockIdx.x * 64;
    int t  = threadIdx.x;
    const float* xb = x + (size_t)b * CIN * NPIX;
    {
        int c  = (t & 15) * 4;
        int r0 = t >> 4;
        #pragma unroll
        for (int i = 0; i < 4; ++i) {
            int ci = r0 + 16*i;
            float4 v = *(const float4*)(xb + (size_t)ci*NPIX + p0 + c);
            tile[ci][c] = v.x; tile[ci][c+1] = v.y; tile[ci][c+2] = v.z; tile[ci][c+3] = v.w;
        }
    }
    __syncthreads();
    {
        int ci4 = (t & 15) * 4;
        int pr  = t >> 4;
        #pragma unroll
        for (int i = 0; i < 4; ++i) {
            int pl = pr + 16*i;
            uint2 w;
            w.x = (unsigned int)f2bf(tile[ci4  ][pl]) | ((unsigned int)f2bf(tile[ci4+1][pl]) << 16);
            w.y = (unsigned int)f2bf(tile[ci4+2][pl]) | ((unsigned int)f2bf(tile[ci4+3][pl]) << 16);
            *(uint2*)(&xT[((size_t)b*NPIX + p0 + pl)*CIN + ci4]) = w;
        }
    }
}

// ---------------- k4: MFMA conv, occupancy-first ----------------
// grid 4608 (16b x 48ty x 6tx), block 256 = 4 waves (co-half mh x row-pair rr).
// Tile: 64co x (4y x 32x); stage 6x34x64 bf16 (26.1 KB) via global_load_lds
// (pre-swizzled source, linear dest), ONE barrier. K-loop: 6 steps (cc x kx),
// each: 6 A-frag L2 loads + 8 B-frag ds_read_b128 (4 rows, reused across 3 ky)
// + 24 MFMA. Occupancy target 5 blocks/CU -> stage latency hidden by other
// blocks' compute (m114 implicit overlap), not by source pipelining.
__global__ __launch_bounds__(256, 5)
void k4_conv(const unsigned short* __restrict__ xT, const unsigned short* __restrict__ Aw,
             float* __restrict__ out) {
    __shared__ unsigned short xs[6*34*64];   // 26112 B
    const int tid = threadIdx.x;

    // bijective XCD swizzle: 4608 % 8 == 0, 576 consecutive wg per XCD
    int bid = blockIdx.x;
    int wg  = (bid & 7) * 576 + (bid >> 3);
    int b   = wg / 288;
    int rem = wg - b*288;
    int ty  = rem / 6;
    int tx  = rem - ty*6;
    const int x0 = tx * 32;
    const int y0 = ty * 4;

    const int wv  = tid >> 6;      // 0..3
    const int mh  = wv >> 1;       // co half 0..1
    const int rr  = wv & 1;        // row pair: output rows 2rr, 2rr+1
    const int l   = tid & 63;
    const int l15 = l & 15;
    const int lg  = l >> 4;        // 0..3

    const unsigned short* xTb = xT + (size_t)b * NPIX * CIN;
    const unsigned short* Al  = Aw + b*(9*COUT*CIN) + (mh*32 + l15)*CIN + lg*8;

    // ---- stage 6 rows x 34 px x 64 ci (pre-swizzled source, linear LDS) ----
    #pragma unroll
    for (int it = 0; it < 7; ++it) {
        int sl = it*256 + tid;
        if (sl < 1632) {
            int swc = sl & 7;
            int P   = sl >> 3;
            int gyl = P / 34;
            int gxl = P - gyl*34;
            int gy = y0 + gyl; if (gy > 191) gy = 191;
            int gx = x0 + gxl; if (gx > 191) gx = 191;
            const void* src = xTb + ((size_t)(gy*HW + gx))*CIN + ((swc ^ (gx & 7)) * 8);
            async_copy16(src, &xs[(size_t)(it*256 + wv*64)*8]);
        }
    }
    __syncthreads();   // drains vmcnt(0): xs ready

    f32x4 acc[2][4] = {};          // [m co-frag][n = r*2+xb2]

    #pragma unroll
    for (int st = 0; st < 6; ++st) {
        const int cc = st / 3, kx = st - 3*(st/3);
        // A: 3-ky column for this (cc,kx), own co-half
        bf16x8 aT[3][2];
        #pragma unroll
        for (int ky = 0; ky < 3; ++ky)
            #pragma unroll
            for (int m = 0; m < 2; ++m)
                aT[ky][m] = *(const bf16x8*)(Al + (ky*3 + kx)*4096 + m*1024 + cc*32);
        // B: 4 row-positions x 2 col-groups, read once, reused across ky
        bf16x8 bb[4][2];
        #pragma unroll
        for (int g = 0; g < 4; ++g)
            #pragma unroll
            for (int xb2 = 0; xb2 < 2; ++xb2) {
                int gyl = rr*2 + g;
                int gxl = xb2*16 + l15 + kx;
                int pch = (cc*4 + lg) ^ (gxl & 7);
                bb[g][xb2] = *(const bf16x8*)(&xs[((gyl*34 + gxl)*8 + pch)*8]);
            }
        #pragma unroll
        for (int ky = 0; ky < 3; ++ky)
            #pragma unroll
            for (int m = 0; m < 2; ++m)
                #pragma unroll
                for (int r = 0; r < 2; ++r)
                    #pragma unroll
                    for (int xb2 = 0; xb2 < 2; ++xb2)
                        acc[m][r*2+xb2] = __builtin_amdgcn_mfma_f32_16x16x32_bf16(
                            aT[ky][m], bb[r+ky][xb2], acc[m][r*2+xb2], 0, 0, 0);
    }

    // ---- epilogue: D col = lane&15 (ox), row = lg*4+j (co) ----
    #pragma unroll
    for (int m = 0; m < 2; ++m)
        #pragma unroll
        for (int r = 0; r < 2; ++r)
            #pragma unroll
            for (int xb2 = 0; xb2 < 2; ++xb2) {
                int oy = y0 + rr*2 + r;
                int ox = x0 + xb2*16 + l15;
                if (oy < OHW && ox < OHW) {
                    f32x4 v = acc[m][r*2+xb2];
                    #pragma unroll
                    for (int j = 0; j < 4; ++j) {
                        int co = mh*32 + m*16 + lg*4 + j;
                        out[((size_t)(b*COUT + co)*OHW + oy)*OHW + ox] = v[j];
                    }
                }
            }
}

extern "C" void kernel_launch(void* const* d_in, const int* in_sizes, int n_in,
                              void* d_out, int out_size, void* d_ws, size_t ws_size,
                              hipStream_t stream) {
    const float* x   = (const float*)d_in[0];
    const float* deg = (const float*)d_in[1];
    const float* W1  = (const float*)d_in[2];
    const float* b1  = (const float*)d_in[3];
    const float* W2  = (const float*)d_in[4];
    const float* b2  = (const float*)d_in[5];
    float* out = (float*)d_out;

    unsigned short* Aw = (unsigned short*)d_ws;                       // 1.18 MB
    unsigned short* xT = (unsigned short*)((char*)d_ws + (size_t)NB*9*COUT*CIN*2);

    k2_wgen<<<NW2/32, 256, 0, stream>>>(deg, W1, b1, W2, b2, Aw);
    k3_transpose<<<dim3(NPIX/64, NB), 256, 0, stream>>>(x, xT);
    k4_conv<<<4608, 256, 0, stream>>>(xT, Aw, out);
}

// Round 8
// 189.192 us; speedup vs baseline: 1.2333x; 1.1280x over previous
//
#include <hip/hip_runtime.h>

// DynamicConv2d: B=16, CIN=COUT=64, K=3, H=W=192, OH=OW=190, DEG=64, HID=256
// out[b][co][oy][ox] = sum_{ci,ky,kx} w[b][co][ci][ky][kx] * x[b][ci][oy+ky][ox+kx]
// w = (relu(deg@W1+b1)@W2+b2).reshape(B,COUT,CIN,3,3)

typedef __bf16 bf16x8 __attribute__((ext_vector_type(8)));
typedef float  f32x4  __attribute__((ext_vector_type(4)));

#define NB   16
#define CIN  64
#define COUT 64
#define HW   192
#define OHW  190
#define NPIX (HW*HW)        // 36864
#define NW2  (COUT*CIN*9)   // 36864

__device__ __forceinline__ unsigned short f2bf(float f) {
    union { float f; unsigned int u; } v; v.f = f;
    unsigned int r = v.u + 0x7FFFu + ((v.u >> 16) & 1u);   // RNE
    return (unsigned short)(r >> 16);
}

// async global->LDS, 16B per lane. LDS dest: wave-uniform base + lane*16.
__device__ __forceinline__ void async_copy16(const void* gsrc, void* ldst) {
    __builtin_amdgcn_global_load_lds(
        (const __attribute__((address_space(1))) unsigned int*)gsrc,
        (__attribute__((address_space(3))) unsigned int*)ldst, 16, 0, 0);
}

// ---------------- k23: transpose (blocks 0..9215) + weight-gen (blocks 9216..10367) ----------------
// Independent workloads share one grid so the latency-bound MLP overlaps the
// BW-bound transpose instead of serializing after it.
__global__ __launch_bounds__(256)
void k23(const float* __restrict__ x, unsigned short* __restrict__ xT,
         const float* __restrict__ deg, const float* __restrict__ W1,
         const float* __restrict__ b1, const float* __restrict__ W2,
         const float* __restrict__ b2, unsigned short* __restrict__ Aw) {
    __shared__ __align__(16) char smem[37376];
    const int bid = blockIdx.x;
    const int t   = threadIdx.x;

    if (bid < 9216) {
        // ---- transpose: xT[b][p][ci] bf16 = x[b][ci][p] ----
        float (*tile)[65] = (float (*)[65])smem;   // 16640 B
        int b  = bid / 576;
        int p0 = (bid - b*576) * 64;
        const float* xb = x + (size_t)b * CIN * NPIX;
        {
            int c  = (t & 15) * 4;
            int r0 = t >> 4;
            #pragma unroll
            for (int i = 0; i < 4; ++i) {
                int ci = r0 + 16*i;
                float4 v = *(const float4*)(xb + (size_t)ci*NPIX + p0 + c);
                tile[ci][c] = v.x; tile[ci][c+1] = v.y; tile[ci][c+2] = v.z; tile[ci][c+3] = v.w;
            }
        }
        __syncthreads();
        {
            int ci8 = (t & 7) * 8;
            int pr0 = t >> 3;        // 0..31
            #pragma unroll
            for (int i = 0; i < 2; ++i) {
                int pl = pr0 + 32*i;
                union { uint4 v; unsigned short u[8]; } pk;
                #pragma unroll
                for (int j = 0; j < 8; ++j) pk.u[j] = f2bf(tile[ci8 + j][pl]);
                *(uint4*)(&xT[((size_t)b*NPIX + p0 + pl)*CIN + ci8]) = pk.v;
            }
        }
    } else {
        // ---- weight generator ----
        float* degs = (float*)smem;                 // 16*64   = 4096 B
        float* hs   = degs + 16*64;                 // 16*256  = 16384 B
        float (*red)[16][33] = (float (*)[16][33])(hs + 16*256);   // 16896 B
        int nb = bid - 9216;                        // 0..1151

        for (int i = t; i < 16*64; i += 256) degs[i] = deg[i];
        __syncthreads();
        {   // h[b][t] for all 16 b
            float acc[16];
            float bias = b1[t];
            #pragma unroll
            for (int bb2 = 0; bb2 < 16; ++bb2) acc[bb2] = bias;
            for (int d = 0; d < 64; ++d) {
                float w = W1[d*256 + t];
                #pragma unroll
                for (int bb2 = 0; bb2 < 16; ++bb2) acc[bb2] += degs[bb2*64 + d] * w;
            }
            #pragma unroll
            for (int bb2 = 0; bb2 < 16; ++bb2) hs[bb2*256 + t] = fmaxf(acc[bb2], 0.f);
        }
        __syncthreads();

        int nl = t & 31;                 // 0..31
        int kc = t >> 5;                 // 0..7
        int n  = nb * 32 + nl;
        float acc[16] = {};
        #pragma unroll
        for (int kk = 0; kk < 32; ++kk) {
            int k = kc*32 + kk;
            float w = W2[(size_t)k*NW2 + n];
            #pragma unroll
            for (int b = 0; b < 16; ++b) acc[b] += hs[b*256 + k] * w;
        }
        #pragma unroll
        for (int b = 0; b < 16; ++b) red[kc][b][nl] = acc[b];
        __syncthreads();

        for (int i = t; i < 512; i += 256) {
            int b  = i >> 5;
            int nn = i & 31;
            int n2 = nb * 32 + nn;
            float s = b2[n2];
            #pragma unroll
            for (int k = 0; k < 8; ++k) s += red[k][b][nn];
            int co  = n2 / 576;
            int rem = n2 - co*576;
            int ci  = rem / 9;
            int tap = rem - ci*9;
            Aw[(((b*9 + tap)*COUT + co)*CIN) + ci] = f2bf(s);
        }
    }
}

// ---------------- k4: MFMA conv (R2-verbatim structure + setprio) ----------------
// grid 2304 (6x * 24y * 16b), block 256 (4 waves). Tile: 64co x (8y x 32x).
// LDS xs: slot s (16B) holds pixel t=s>>3, chunk swc=s&7, where the SOURCE chunk is
// c = swc ^ (gx&7)  (pre-swizzled global source, linear LDS dest -> global_load_lds OK).
// A-fragments double-buffered in registers (prefetch tap+1 during tap's MFMAs).
// s_setprio(1) around MFMA clusters: 3 desynced blocks/CU -> compute-phase block
// wins issue slots over stage-phase blocks (T5, m191 independent-block case).
#define XS_SLOTS 2816   // ceil(10*34*8 / 256)*256
__global__ __launch_bounds__(256, 3)
void k4_conv(const unsigned short* __restrict__ xT, const unsigned short* __restrict__ Aw,
             float* __restrict__ out) {
    __shared__ unsigned short xs[XS_SLOTS*8];   // 45056 B
    const int tid = threadIdx.x;

    // bijective XCD swizzle: 2304 % 8 == 0, 288 consecutive tiles per XCD
    int bid = blockIdx.x;
    int wg  = (bid & 7) * 288 + (bid >> 3);
    int b   = wg / 144;
    int ry  = wg - b*144;
    int ty  = ry / 6;
    int tx  = ry - ty*6;
    const int x0 = tx * 32;
    const int y0 = ty * 8;

    const int wv  = tid >> 6;    // wave 0..3 -> rows 2wv, 2wv+1
    const int l   = tid & 63;
    const int l15 = l & 15;
    const int lg  = l >> 4;      // 0..3

    // ---- stage input tile via global_load_lds (pre-swizzled source) ----
    const unsigned short* xTb = xT + (size_t)b * NPIX * CIN;
    #pragma unroll
    for (int it = 0; it < 11; ++it) {
        int s   = it*256 + tid;
        int t   = s >> 3;
        int swc = s & 7;
        int gyl = t / 34;
        int gxl = t - gyl*34;
        int gy  = y0 + gyl; gy = gy > 191 ? 191 : gy;
        int gx  = x0 + gxl; gx = gx > 191 ? 191 : gx;
        const void* src = xTb + ((size_t)(gy*HW + gx))*CIN + ((swc ^ (gx & 7)) * 8);
        void* dst = &xs[(it*256 + wv*64) * 8];
        async_copy16(src, dst);
    }

    // ---- prefetch A for tap 0 while staging drains ----
    const unsigned short* Ab = Aw + b * (9*COUT*CIN);
    const unsigned short* Al = Ab + l15*CIN + lg*8;   // lane base
    bf16x8 a[2][8];   // [buf][cc*4+m]
    #pragma unroll
    for (int cc = 0; cc < 2; ++cc)
        #pragma unroll
        for (int m = 0; m < 4; ++m)
            a[0][cc*4+m] = *(const bf16x8*)(Al + m*1024 + cc*32);

    __syncthreads();   // drains vmcnt(0) -> xs + a[0] ready

    f32x4 acc[4][4] = {};        // [m co-group][n = r*2+xb]

    #pragma unroll
    for (int tap = 0; tap < 9; ++tap) {
        const int cur = tap & 1, nxt = cur ^ 1;
        if (tap < 8) {
            #pragma unroll
            for (int cc = 0; cc < 2; ++cc)
                #pragma unroll
                for (int m = 0; m < 4; ++m)
                    a[nxt][cc*4+m] = *(const bf16x8*)(Al + (tap+1)*4096 + m*1024 + cc*32);
        }
        const int ky = tap / 3, kx = tap - 3*(tap/3);
        #pragma unroll
        for (int cc = 0; cc < 2; ++cc) {
            bf16x8 bb[4];
            #pragma unroll
            for (int r = 0; r < 2; ++r)
                #pragma unroll
                for (int xb = 0; xb < 2; ++xb) {
                    int gyl = 2*wv + r + ky;
                    int gxl = xb*16 + l15 + kx;
                    int pch = (cc*4 + lg) ^ (gxl & 7);
                    bb[r*2 + xb] = *(const bf16x8*)(&xs[((gyl*34 + gxl)*8 + pch)*8]);
                }
            __builtin_amdgcn_s_setprio(1);
            #pragma unroll
            for (int m = 0; m < 4; ++m)
                #pragma unroll
                for (int n = 0; n < 4; ++n)
                    acc[m][n] = __builtin_amdgcn_mfma_f32_16x16x32_bf16(a[cur][cc*4+m], bb[n], acc[m][n], 0, 0, 0);
            __builtin_amdgcn_s_setprio(0);
        }
    }

    // ---- epilogue: D col = lane&15 (spatial), row = (lane>>4)*4+j (co) ----
    #pragma unroll
    for (int m = 0; m < 4; ++m)
        #pragma unroll
        for (int r = 0; r < 2; ++r)
            #pragma unroll
            for (int xb = 0; xb < 2; ++xb) {
                int oy = y0 + 2*wv + r;
                int ox = x0 + xb*16 + l15;
                if (oy < OHW && ox < OHW) {
                    f32x4 v = acc[m][r*2 + xb];
                    #pragma unroll
                    for (int j = 0; j < 4; ++j) {
                        int co = m*16 + lg*4 + j;
                        out[((size_t)(b*COUT + co)*OHW + oy)*OHW + ox] = v[j];
                    }
                }
            }
}

extern "C" void kernel_launch(void* const* d_in, const int* in_sizes, int n_in,
                              void* d_out, int out_size, void* d_ws, size_t ws_size,
                              hipStream_t stream) {
    const float* x   = (const float*)d_in[0];
    const float* deg = (const float*)d_in[1];
    const float* W1  = (const float*)d_in[2];
    const float* b1  = (const float*)d_in[3];
    const float* W2  = (const float*)d_in[4];
    const float* b2  = (const float*)d_in[5];
    float* out = (float*)d_out;

    unsigned short* Aw = (unsigned short*)d_ws;                       // 1.18 MB
    unsigned short* xT = (unsigned short*)((char*)d_ws + (size_t)NB*9*COUT*CIN*2);

    k23<<<9216 + 1152, 256, 0, stream>>>(x, xT, deg, W1, b1, W2, b2, Aw);
    k4_conv<<<2304, 256, 0, stream>>>(xT, Aw, out);
}